// Round 1
// baseline (2673.398 us; speedup 1.0000x reference)
//
#include <hip/hip_runtime.h>
#include <stdint.h>

// Problem constants (from reference): B=512 queries, N=262144 index rows,
// D=512 dims, K=10. Output: int32 indices [512,10], sorted by sim desc,
// ties broken by lower index (jax.lax.top_k semantics).
#define B_Q   512
#define N_IDX 262144
#define D_DIM 512
#define TOPK  10

constexpr int BM = 128;              // query rows per block
constexpr int BN = 64;               // index rows (output cols) per tile
constexpr int BK = 32;               // K tile
constexpr int NCHUNK = 128;          // N-chunks (phase-1 blocks along N)
constexpr int NR = N_IDX / NCHUNK;   // 2048 cols per block
constexpr int NTILES = NR / BN;      // 32
constexpr int KTILES = D_DIM / BK;   // 16

// LDS strides (floats). As/Bs padded +4 to keep float4 alignment and spread
// banks; Cs padded +1 (odd stride -> conflict-free column scans, scalar access).
constexpr int AS = BM + 4;           // 132
constexpr int BS = BN + 4;           // 68
constexpr int CS = BN + 1;           // 65

// Phase 1: fused fp32 GEMM tile + running per-row top-10 over this block's
// 2048-column N-range. Grid: (NCHUNK, B_Q/BM). Block: 256.
__global__ __launch_bounds__(256, 2)
void faiss_p1_gemm_topk(const float* __restrict__ Q, const float* __restrict__ X,
                        float* __restrict__ cand_v, int* __restrict__ cand_i)
{
    __shared__ float As[BK][AS];     // A tile transposed: As[k][row]
    __shared__ float Bs[BK][BS];     // B tile transposed: Bs[k][col]
    __shared__ float Cs[BM][CS];     // sims tile for epilogue scan

    const int tid = threadIdx.x;
    const int tx  = tid & 15;        // col group: owns cols tx*4..tx*4+3
    const int ty  = tid >> 4;        // row group: owns rows ty*8..ty*8+7
    const int bc  = blockIdx.x;      // N-chunk id
    const int bq  = blockIdx.y;      // query tile id
    const int row0 = bq * BM;

    // running top-10 (sorted descending) per row-owner thread (tid < 128)
    float topv[TOPK];
    int   topi[TOPK];
#pragma unroll
    for (int j = 0; j < TOPK; ++j) { topv[j] = -3.0e38f; topi[j] = 0; }

    for (int nt = 0; nt < NTILES; ++nt) {
        const int col0 = bc * NR + nt * BN;

        float acc[8][4];
#pragma unroll
        for (int i = 0; i < 8; ++i)
#pragma unroll
            for (int j = 0; j < 4; ++j) acc[i][j] = 0.0f;

        for (int kt = 0; kt < KTILES; ++kt) {
            // stage A (128 rows x 32 k), transposed into As[k][row]
#pragma unroll
            for (int i = 0; i < 4; ++i) {
                const int f  = tid + i * 256;     // float4 id 0..1023
                const int r  = f >> 3;            // 0..127
                const int c4 = (f & 7) << 2;      // k offset 0..28
                const float4 v = *reinterpret_cast<const float4*>(
                    &Q[(row0 + r) * D_DIM + kt * BK + c4]);
                As[c4 + 0][r] = v.x;
                As[c4 + 1][r] = v.y;
                As[c4 + 2][r] = v.z;
                As[c4 + 3][r] = v.w;
            }
            // stage B (64 rows x 32 k), transposed into Bs[k][col]
#pragma unroll
            for (int i = 0; i < 2; ++i) {
                const int f  = tid + i * 256;     // float4 id 0..511
                const int r  = f >> 3;            // 0..63
                const int c4 = (f & 7) << 2;
                const float4 v = *reinterpret_cast<const float4*>(
                    &X[(size_t)(col0 + r) * D_DIM + kt * BK + c4]);
                Bs[c4 + 0][r] = v.x;
                Bs[c4 + 1][r] = v.y;
                Bs[c4 + 2][r] = v.z;
                Bs[c4 + 3][r] = v.w;
            }
            __syncthreads();

#pragma unroll
            for (int k = 0; k < BK; ++k) {
                const float4 a0 = *reinterpret_cast<const float4*>(&As[k][ty * 8]);
                const float4 a1 = *reinterpret_cast<const float4*>(&As[k][ty * 8 + 4]);
                const float4 b  = *reinterpret_cast<const float4*>(&Bs[k][tx * 4]);
                const float av[8] = {a0.x, a0.y, a0.z, a0.w, a1.x, a1.y, a1.z, a1.w};
                const float bv[4] = {b.x, b.y, b.z, b.w};
#pragma unroll
                for (int i = 0; i < 8; ++i)
#pragma unroll
                    for (int j = 0; j < 4; ++j)
                        acc[i][j] = fmaf(av[i], bv[j], acc[i][j]);
            }
            __syncthreads();
        }

        // dump tile to LDS for the row-wise scan
#pragma unroll
        for (int i = 0; i < 8; ++i)
#pragma unroll
            for (int j = 0; j < 4; ++j)
                Cs[ty * 8 + i][tx * 4 + j] = acc[i][j];
        __syncthreads();

        // row-owner threads merge this tile's 64 candidates into running top-10.
        // Strict '>' keeps earlier (lower) index on exact ties; columns are
        // scanned in increasing global index order, so tie semantics match
        // jax.lax.top_k (lower index first).
        if (tid < BM) {
            const int r = tid;
            for (int c = 0; c < BN; ++c) {
                const float v = Cs[r][c];
                if (v > topv[TOPK - 1]) {
                    topv[TOPK - 1] = v;
                    topi[TOPK - 1] = col0 + c;
#pragma unroll
                    for (int j = TOPK - 1; j > 0; --j) {
                        if (topv[j] > topv[j - 1]) {
                            const float tv = topv[j]; topv[j] = topv[j - 1]; topv[j - 1] = tv;
                            const int   ti = topi[j]; topi[j] = topi[j - 1]; topi[j - 1] = ti;
                        }
                    }
                }
            }
        }
        __syncthreads();
    }

    // emit this (row, chunk)'s sorted top-10 candidates
    if (tid < BM) {
        const size_t base = ((size_t)(row0 + tid) * NCHUNK + bc) * TOPK;
#pragma unroll
        for (int j = 0; j < TOPK; ++j) {
            cand_v[base + j] = topv[j];
            cand_i[base + j] = topi[j];
        }
    }
}

constexpr int NCAND = NCHUNK * TOPK;   // 1280 candidates per row

// Phase 2: exact rank-selection merge. One block per query row.
// Total order: (value desc, index asc) -> ranks are unique; each candidate
// with rank < 10 writes its own output slot. Deterministic, race-free.
__global__ __launch_bounds__(256)
void faiss_p2_merge(const float* __restrict__ cand_v, const int* __restrict__ cand_i,
                    int* __restrict__ out)
{
    __shared__ float vs[NCAND];
    __shared__ int   is[NCAND];
    const int row = blockIdx.x;
    const int tid = threadIdx.x;

    for (int i = tid; i < NCAND; i += 256) {
        vs[i] = cand_v[(size_t)row * NCAND + i];
        is[i] = cand_i[(size_t)row * NCAND + i];
    }
    __syncthreads();

    for (int c = tid; c < NCAND; c += 256) {
        const float v  = vs[c];
        const int   id = is[c];
        int rank = 0;
        for (int j = 0; j < NCAND; ++j) {
            const float vj = vs[j];
            rank += (vj > v) || (vj == v && is[j] < id);
        }
        if (rank < TOPK) out[row * TOPK + rank] = id;
    }
}

extern "C" void kernel_launch(void* const* d_in, const int* in_sizes, int n_in,
                              void* d_out, int out_size, void* d_ws, size_t ws_size,
                              hipStream_t stream)
{
    const float* Q = (const float*)d_in[0];   // [512, 512]
    const float* X = (const float*)d_in[1];   // [262144, 512]
    // d_in[2] is k (always 10; reference bakes K=10) — TOPK hardcoded.
    int* out = (int*)d_out;                   // [512, 10] int32

    float* cand_v = (float*)d_ws;
    int*   cand_i = (int*)((char*)d_ws + (size_t)B_Q * NCHUNK * TOPK * sizeof(float));
    // workspace use: 512*128*10*(4+4) = 5.24 MB

    dim3 g1(NCHUNK, B_Q / BM);   // (128, 4)
    faiss_p1_gemm_topk<<<g1, dim3(256), 0, stream>>>(Q, X, cand_v, cand_i);
    faiss_p2_merge<<<dim3(B_Q), dim3(256), 0, stream>>>(cand_v, cand_i, out);
}

// Round 2
// 1947.790 us; speedup vs baseline: 1.3725x; 1.3725x over previous
//
#include <hip/hip_runtime.h>
#include <stdint.h>

// IndexFlatIP top-k: sims = Q[512,512] @ X[262144,512]^T, per-row top-10
// indices (desc, ties -> lower index). Output int32 [512,10].
//
// Phase 1: MFMA GEMM with f16 hi/lo split (3 products, lo scaled by 2^11 to
// dodge f16 denormals; merged as acc + acc2/2048) + fused per-row running
// top-10 over each block's N-range. Phase 2: exact rank-merge (unchanged
// from the passing round-1 kernel).
#define B_Q   512
#define N_IDX 262144
#define D_DIM 512
#define TOPK  10

constexpr int BM = 128;              // query rows per block
constexpr int BN = 128;              // index rows per tile
constexpr int BK = 32;               // K step (one mfma_16x16x32)
constexpr int NCHUNK = 128;          // blocks along N
constexpr int NR = N_IDX / NCHUNK;   // 2048 cols per block
constexpr int NTILES = NR / BN;      // 16
constexpr int KTILES = D_DIM / BK;   // 16

typedef _Float16 half8 __attribute__((ext_vector_type(8)));
typedef float    f32x4 __attribute__((ext_vector_type(4)));

// Convert 8 consecutive fp32 to f16 hi + scaled-lo granules (16 B each).
__device__ inline void cvt8(const float* __restrict__ src,
                            _Float16* __restrict__ dh, _Float16* __restrict__ dl)
{
    const float4 p0 = *reinterpret_cast<const float4*>(src);
    const float4 p1 = *reinterpret_cast<const float4*>(src + 4);
    const float x[8] = {p0.x, p0.y, p0.z, p0.w, p1.x, p1.y, p1.z, p1.w};
    half8 h, l;
#pragma unroll
    for (int e = 0; e < 8; ++e) {
        const _Float16 hh = (_Float16)x[e];
        h[e] = hh;
        l[e] = (_Float16)((x[e] - (float)hh) * 2048.0f);  // lo * 2^11: f16-normal
    }
    *reinterpret_cast<half8*>(dh) = h;
    *reinterpret_cast<half8*>(dl) = l;
}

// Phase 1. Grid (NCHUNK, 4), block 256 (4 waves: 2M x 2N, wave tile 64x64).
// LDS (32 KB): slot-major f16 tiles Ah/Al/Bh/Bl (granule = 8 f16 = 16 B,
// addr = (slot*128 + row)*16B) -> conflict-optimal ds_read_b128 fragments.
// Epilogue overlays a 128x64 fp32 scratch (XOR-swizzled) on the same LDS.
__global__ __launch_bounds__(256, 2)
void faiss_p1_mfma(const float* __restrict__ Q, const float* __restrict__ X,
                   float* __restrict__ cand_v, int* __restrict__ cand_i)
{
    __shared__ __align__(16) char smem[32768];
    _Float16* Ah = (_Float16*)(smem);            // 8 KB: 4 slots x 128 rows x 8
    _Float16* Al = (_Float16*)(smem + 8192);
    _Float16* Bh = (_Float16*)(smem + 16384);
    _Float16* Bl = (_Float16*)(smem + 24576);
    float*    Cs = (float*)(smem);               // overlay: 128 x 64 fp32

    const int tid  = threadIdx.x;
    const int lane = tid & 63;
    const int wid  = tid >> 6;
    const int wm   = wid >> 1;       // 0..1 (M half)
    const int wn   = wid & 1;        // 0..1 (N half)
    const int bc   = blockIdx.x;
    const int row0 = blockIdx.y * BM;

    // staging assignment: 1024 granules (A:512, B:512), 4 per thread.
    // it 0,1 -> A granules (gid = it*256+tid), it 2,3 -> B.
    int g_row[4], g_slot[4], g_dst[4];
#pragma unroll
    for (int it = 0; it < 4; ++it) {
        const int g = ((it & 1) << 8) + tid;     // 0..511 within A or B half
        g_row[it]  = g >> 2;                     // 0..127
        g_slot[it] = g & 3;                      // 0..3
        g_dst[it]  = (g_slot[it] * 128 + g_row[it]) * 8;
    }

    // fragment LDS element offsets (8 f16 per lane per fragment)
    int a_off[4], b_off[4];
#pragma unroll
    for (int i = 0; i < 4; ++i) {
        a_off[i] = ((lane >> 4) * 128 + wm * 64 + i * 16 + (lane & 15)) * 8;
        b_off[i] = ((lane >> 4) * 128 + wn * 64 + i * 16 + (lane & 15)) * 8;
    }

    float topv[TOPK]; int topi[TOPK];
#pragma unroll
    for (int j = 0; j < TOPK; ++j) { topv[j] = -3.0e38f; topi[j] = 0; }

    for (int nt = 0; nt < NTILES; ++nt) {
        const int col0 = bc * NR + nt * BN;

        f32x4 acc[4][4], acc2[4][4];
#pragma unroll
        for (int i = 0; i < 4; ++i)
#pragma unroll
            for (int j = 0; j < 4; ++j) {
                acc[i][j] = (f32x4)0.0f; acc2[i][j] = (f32x4)0.0f;
            }

        for (int kt = 0; kt < KTILES; ++kt) {
            const int kb = kt * BK;
            // stage A (Q) granules
#pragma unroll
            for (int it = 0; it < 2; ++it) {
                const float* src = Q + (size_t)(row0 + g_row[it]) * D_DIM + kb + g_slot[it] * 8;
                cvt8(src, Ah + g_dst[it], Al + g_dst[it]);
            }
            // stage B (X) granules
#pragma unroll
            for (int it = 2; it < 4; ++it) {
                const float* src = X + (size_t)(col0 + g_row[it]) * D_DIM + kb + g_slot[it] * 8;
                cvt8(src, Bh + g_dst[it], Bl + g_dst[it]);
            }
            __syncthreads();

            half8 ah[4], al[4];
#pragma unroll
            for (int mi = 0; mi < 4; ++mi) {
                ah[mi] = *reinterpret_cast<half8*>(&Ah[a_off[mi]]);
                al[mi] = *reinterpret_cast<half8*>(&Al[a_off[mi]]);
            }
#pragma unroll
            for (int ni = 0; ni < 4; ++ni) {
                const half8 bh = *reinterpret_cast<half8*>(&Bh[b_off[ni]]);
                const half8 bl = *reinterpret_cast<half8*>(&Bl[b_off[ni]]);
#pragma unroll
                for (int mi = 0; mi < 4; ++mi) {
                    acc [mi][ni] = __builtin_amdgcn_mfma_f32_16x16x32_f16(ah[mi], bh, acc [mi][ni], 0, 0, 0);
                    acc2[mi][ni] = __builtin_amdgcn_mfma_f32_16x16x32_f16(al[mi], bh, acc2[mi][ni], 0, 0, 0);
                    acc2[mi][ni] = __builtin_amdgcn_mfma_f32_16x16x32_f16(ah[mi], bl, acc2[mi][ni], 0, 0, 0);
                }
            }
            __syncthreads();
        }

        // epilogue: two column-halves; dump (swizzled) -> scan into top-10.
        // C/D layout (verified m89): col = lane&15, row = (lane>>4)*4 + reg.
#pragma unroll
        for (int h = 0; h < 2; ++h) {
            if (wn == h) {
#pragma unroll
                for (int mi = 0; mi < 4; ++mi)
#pragma unroll
                    for (int ni = 0; ni < 4; ++ni)
#pragma unroll
                        for (int r = 0; r < 4; ++r) {
                            const int row = wm * 64 + mi * 16 + (lane >> 4) * 4 + r;
                            const int c   = ni * 16 + (lane & 15);
                            Cs[row * 64 + (c ^ (row & 31))] =
                                acc[mi][ni][r] + acc2[mi][ni][r] * (1.0f / 2048.0f);
                        }
            }
            __syncthreads();
            if (tid < BM) {
                const int r = tid;
                const int base = col0 + h * 64;
                for (int c = 0; c < 64; ++c) {
                    const float v  = Cs[r * 64 + (c ^ (r & 31))];
                    const int   id = base + c;
                    // total order (v desc, idx asc) -> scan order irrelevant
                    if (v > topv[TOPK - 1] ||
                        (v == topv[TOPK - 1] && id < topi[TOPK - 1])) {
                        topv[TOPK - 1] = v; topi[TOPK - 1] = id;
#pragma unroll
                        for (int j = TOPK - 1; j > 0; --j) {
                            const bool gt = topv[j] > topv[j - 1] ||
                                (topv[j] == topv[j - 1] && topi[j] < topi[j - 1]);
                            if (gt) {
                                const float tv = topv[j]; topv[j] = topv[j - 1]; topv[j - 1] = tv;
                                const int   ti = topi[j]; topi[j] = topi[j - 1]; topi[j - 1] = ti;
                            }
                        }
                    }
                }
            }
            __syncthreads();
        }
    }

    if (tid < BM) {
        const size_t base = ((size_t)(row0 + tid) * NCHUNK + bc) * TOPK;
#pragma unroll
        for (int j = 0; j < TOPK; ++j) {
            cand_v[base + j] = topv[j];
            cand_i[base + j] = topi[j];
        }
    }
}

constexpr int NCAND = NCHUNK * TOPK;   // 1280 per row

// Phase 2: exact rank-selection merge (total order: value desc, index asc).
__global__ __launch_bounds__(256)
void faiss_p2_merge(const float* __restrict__ cand_v, const int* __restrict__ cand_i,
                    int* __restrict__ out)
{
    __shared__ float vs[NCAND];
    __shared__ int   is[NCAND];
    const int row = blockIdx.x;
    const int tid = threadIdx.x;

    for (int i = tid; i < NCAND; i += 256) {
        vs[i] = cand_v[(size_t)row * NCAND + i];
        is[i] = cand_i[(size_t)row * NCAND + i];
    }
    __syncthreads();

    for (int c = tid; c < NCAND; c += 256) {
        const float v  = vs[c];
        const int   id = is[c];
        int rank = 0;
        for (int j = 0; j < NCAND; ++j) {
            const float vj = vs[j];
            rank += (vj > v) || (vj == v && is[j] < id);
        }
        if (rank < TOPK) out[row * TOPK + rank] = id;
    }
}

extern "C" void kernel_launch(void* const* d_in, const int* in_sizes, int n_in,
                              void* d_out, int out_size, void* d_ws, size_t ws_size,
                              hipStream_t stream)
{
    const float* Q = (const float*)d_in[0];   // [512, 512]
    const float* X = (const float*)d_in[1];   // [262144, 512]
    int* out = (int*)d_out;                   // [512, 10] int32

    float* cand_v = (float*)d_ws;
    int*   cand_i = (int*)((char*)d_ws + (size_t)B_Q * NCHUNK * TOPK * sizeof(float));
    // workspace: 512*128*10*8 B = 5.24 MB

    dim3 g1(NCHUNK, B_Q / BM);   // (128, 4)
    faiss_p1_mfma<<<g1, dim3(256), 0, stream>>>(Q, X, cand_v, cand_i);
    faiss_p2_merge<<<dim3(B_Q), dim3(256), 0, stream>>>(cand_v, cand_i, out);
}